// Round 3
// baseline (2249.941 us; speedup 1.0000x reference)
//
#include <hip/hip_runtime.h>
#include <math.h>

#define T_STEPS 8
#define N_NODES 20000
#define F_IN    128
#define H_DIM   256
#define E_EDGES 320000

#define G_UPD    625     // update tiles (20000/32)
#define G_BIG    640     // 80 row-groups x 8 chunks; blocks 625..639 gather-only
#define ROWS_PER_GROUP 250   // 80 * 250 = 20000

typedef __attribute__((ext_vector_type(8))) short short8;
typedef __attribute__((ext_vector_type(4))) float f32x4;

__device__ __forceinline__ void split2(float v, unsigned short& h, unsigned short& l) {
    unsigned vi = __float_as_uint(v);
    h = (unsigned short)(vi >> 16);
    float hf = __uint_as_float(vi & 0xffff0000u);
    l = (unsigned short)(__float_as_uint(v - hf) >> 16);
}

// ---------------- CSR build ----------------

__global__ void count_kernel(const int* __restrict__ dst, int* __restrict__ counts, int E) {
    int e = blockIdx.x * blockDim.x + threadIdx.x;
    if (e < E) atomicAdd(&counts[dst[e]], 1);
}

__global__ void scan_kernel(const int* __restrict__ counts, int* __restrict__ row_ptr,
                            int* __restrict__ cursors, int n) {
    __shared__ int buf[1024];
    __shared__ int carry_s;
    int tid = threadIdx.x;
    if (tid == 0) carry_s = 0;
    __syncthreads();
    for (int base = 0; base < n; base += 1024) {
        int i = base + tid;
        int v = (i < n) ? counts[i] : 0;
        buf[tid] = v;
        __syncthreads();
        for (int off = 1; off < 1024; off <<= 1) {
            int t = (tid >= off) ? buf[tid - off] : 0;
            __syncthreads();
            buf[tid] += t;
            __syncthreads();
        }
        int incl = buf[tid];
        int carry = carry_s;
        if (i < n) {
            int ex = carry + incl - v;
            row_ptr[i] = ex;
            cursors[i] = ex;
        }
        __syncthreads();
        if (tid == 1023) carry_s = carry + incl;
        __syncthreads();
    }
    if (tid == 0) row_ptr[n] = carry_s;
}

// col stored as ushort (N_NODES < 65536): halves index traffic, helps L2 residency
__global__ void fill_kernel(const int* __restrict__ src, const int* __restrict__ dst,
                            int* __restrict__ cursors, unsigned short* __restrict__ col, int E) {
    int e = blockIdx.x * blockDim.x + threadIdx.x;
    if (e < E) {
        int d = dst[e];
        int p = atomicAdd(&cursors[d], 1);
        col[p] = (unsigned short)src[e];
    }
}

// ---------------- weight fp32 -> MFMA-fragment-major bf16 hi/lo ----------------

__global__ void cvt_frag(const float* __restrict__ W, int K,
                         unsigned short* __restrict__ fh, unsigned short* __restrict__ fl) {
    int g = blockIdx.x * 256 + threadIdx.x;
    int KP32 = K >> 5;
    int total = (H_DIM / 16) * KP32 * 64;
    if (g >= total) return;
    int lane = g & 63;
    int kp = (g >> 6) % KP32;
    int rt = g / (KP32 << 6);
    int r = rt * 16 + (lane & 15);
    int c = kp * 32 + (lane >> 4) * 8;
    const float* p = W + (size_t)r * K + c;
    short8 h, l;
    #pragma unroll
    for (int j = 0; j < 8; ++j) {
        unsigned short hh, ll;
        split2(p[j], hh, ll);
        h[j] = (short)hh; l[j] = (short)ll;
    }
    *(short8*)(fh + (size_t)g * 8) = h;
    *(short8*)(fl + (size_t)g * 8) = l;
}

// ---------------- fat-block step kernel ----------------
// 512 threads: waves 0-3 = dense MFMA update tile (blocks < G_UPD, 32 rows x 256
// cols), waves 4-7 = column-chunked gather for chunk = blockIdx&7 (XCD-pinned:
// r2 confirmed FETCH 300->44 MB with this mapping). Same block -> update and
// gather co-resident on every CU by construction (r2's failure mode was the
// 5000-gather-then-625-update dispatch-order phase serialization: 26% occ tail).
// Gather processes 4 rows per iteration with 4 independent col->src load chains
// in flight per lane (r2 had 1 chain -> latency-bound).

__global__ __launch_bounds__(512) void step_kernel(
        const float* __restrict__ A1, int K1,
        const float* __restrict__ s_prev,
        const unsigned short* __restrict__ B1h, const unsigned short* __restrict__ B1l,
        const unsigned short* __restrict__ B2h, const unsigned short* __restrict__ B2l,
        const float* __restrict__ AGGu,
        float* __restrict__ s_new,
        const float* __restrict__ gsrc, float* __restrict__ gout, int do_gather,
        const int* __restrict__ row_ptr, const unsigned short* __restrict__ col,
        const float* __restrict__ leak_ptr) {
    const int tid = threadIdx.x;
    const int lane = tid & 63, w = tid >> 6;

    if (tid >= 256) {
        // ---------------- gather waves (4..7) ----------------
        if (!do_gather) return;
        const int chunk = blockIdx.x & 7;          // XCD pin
        const int g = blockIdx.x >> 3;             // row group [0,80)
        const int wg = w - 4;
        const int slot = lane >> 3, comp = lane & 7;
        const float4* src4 = (const float4*)gsrc + (size_t)chunk * 8 + comp;
        const int rbase = g * ROWS_PER_GROUP;
        const int r0 = rbase + wg * 63;
        const int rend = min(rbase + ROWS_PER_GROUP, r0 + 63);

        for (int r = r0; r < rend; r += 4) {
            // per-row validity + row_ptr (clamped so loads stay in-bounds)
            int rv[4], bg[4], en[4];
            #pragma unroll
            for (int k = 0; k < 4; ++k) {
                int rk = r + k;
                bool hv = rk < rend;
                int rkc = hv ? rk : r;
                bg[k] = row_ptr[rkc];
                en[k] = hv ? row_ptr[rkc + 1] : bg[k];
                rv[k] = hv;
            }
            float4 a0 = {0,0,0,0}, a1 = {0,0,0,0}, a2 = {0,0,0,0}, a3 = {0,0,0,0};
            int j0 = bg[0] + slot, j1 = bg[1] + slot, j2 = bg[2] + slot, j3 = bg[3] + slot;
            bool o0 = j0 < en[0], o1 = j1 < en[1], o2 = j2 < en[2], o3 = j3 < en[3];
            while (o0 || o1 || o2 || o3) {
                int i0 = col[o0 ? j0 : 0];
                int i1 = col[o1 ? j1 : 0];
                int i2 = col[o2 ? j2 : 0];
                int i3 = col[o3 ? j3 : 0];
                float4 v0 = src4[(size_t)i0 * 64];
                float4 v1 = src4[(size_t)i1 * 64];
                float4 v2 = src4[(size_t)i2 * 64];
                float4 v3 = src4[(size_t)i3 * 64];
                if (o0) { a0.x += v0.x; a0.y += v0.y; a0.z += v0.z; a0.w += v0.w; j0 += 8; }
                if (o1) { a1.x += v1.x; a1.y += v1.y; a1.z += v1.z; a1.w += v1.w; j1 += 8; }
                if (o2) { a2.x += v2.x; a2.y += v2.y; a2.z += v2.z; a2.w += v2.w; j2 += 8; }
                if (o3) { a3.x += v3.x; a3.y += v3.y; a3.z += v3.z; a3.w += v3.w; j3 += 8; }
                o0 = j0 < en[0]; o1 = j1 < en[1]; o2 = j2 < en[2]; o3 = j3 < en[3];
            }
            // cross-slot reduce (slots differ in lane bits 3..5)
            #pragma unroll
            for (int m = 8; m < 64; m <<= 1) {
                a0.x += __shfl_xor(a0.x, m); a0.y += __shfl_xor(a0.y, m);
                a0.z += __shfl_xor(a0.z, m); a0.w += __shfl_xor(a0.w, m);
                a1.x += __shfl_xor(a1.x, m); a1.y += __shfl_xor(a1.y, m);
                a1.z += __shfl_xor(a1.z, m); a1.w += __shfl_xor(a1.w, m);
                a2.x += __shfl_xor(a2.x, m); a2.y += __shfl_xor(a2.y, m);
                a2.z += __shfl_xor(a2.z, m); a2.w += __shfl_xor(a2.w, m);
                a3.x += __shfl_xor(a3.x, m); a3.y += __shfl_xor(a3.y, m);
                a3.z += __shfl_xor(a3.z, m); a3.w += __shfl_xor(a3.w, m);
            }
            if (slot == 0) {
                if (rv[0]) *(float4*)(gout + (size_t)(r    ) * 256 + chunk * 32 + comp * 4) = a0;
                if (rv[1]) *(float4*)(gout + (size_t)(r + 1) * 256 + chunk * 32 + comp * 4) = a1;
                if (rv[2]) *(float4*)(gout + (size_t)(r + 2) * 256 + chunk * 32 + comp * 4) = a2;
                if (rv[3]) *(float4*)(gout + (size_t)(r + 3) * 256 + chunk * 32 + comp * 4) = a3;
            }
        }
        return;
    }

    // ---------------- update waves (0..3) ----------------
    if (blockIdx.x >= G_UPD) return;
    const int m0 = blockIdx.x * 32;
    const int fr = lane & 15, fq = lane >> 4;
    const int wn = w * 64;
    const int rtbase = w * 4;

    f32x4 acc[2][4];
    #pragma unroll
    for (int mi = 0; mi < 2; ++mi)
        #pragma unroll
        for (int nt = 0; nt < 4; ++nt)
            acc[mi][nt] = (f32x4){0.f, 0.f, 0.f, 0.f};

    // ---- part 1: dense A1 ----
    {
        const int KP32 = K1 >> 5;
        #pragma unroll 1
        for (int kp = 0; kp < KP32; ++kp) {
            short8 ah[2], al[2];
            #pragma unroll
            for (int mi = 0; mi < 2; ++mi) {
                const float* ap = A1 + (size_t)(m0 + mi * 16 + fr) * K1 + kp * 32 + fq * 8;
                float4 v0 = *(const float4*)ap;
                float4 v1 = *(const float4*)(ap + 4);
                unsigned short h, l;
                split2(v0.x, h, l); ah[mi][0] = (short)h; al[mi][0] = (short)l;
                split2(v0.y, h, l); ah[mi][1] = (short)h; al[mi][1] = (short)l;
                split2(v0.z, h, l); ah[mi][2] = (short)h; al[mi][2] = (short)l;
                split2(v0.w, h, l); ah[mi][3] = (short)h; al[mi][3] = (short)l;
                split2(v1.x, h, l); ah[mi][4] = (short)h; al[mi][4] = (short)l;
                split2(v1.y, h, l); ah[mi][5] = (short)h; al[mi][5] = (short)l;
                split2(v1.z, h, l); ah[mi][6] = (short)h; al[mi][6] = (short)l;
                split2(v1.w, h, l); ah[mi][7] = (short)h; al[mi][7] = (short)l;
            }
            short8 bh[4], bl[4];
            #pragma unroll
            for (int nt = 0; nt < 4; ++nt) {
                size_t off = ((size_t)((rtbase + nt) * KP32 + kp) * 64 + lane) * 8;
                bh[nt] = *(const short8*)(B1h + off);
                bl[nt] = *(const short8*)(B1l + off);
            }
            #pragma unroll
            for (int mi = 0; mi < 2; ++mi)
                #pragma unroll
                for (int nt = 0; nt < 4; ++nt) {
                    f32x4 c = acc[mi][nt];
                    c = __builtin_amdgcn_mfma_f32_16x16x32_bf16(ah[mi], bh[nt], c, 0, 0, 0);
                    c = __builtin_amdgcn_mfma_f32_16x16x32_bf16(al[mi], bh[nt], c, 0, 0, 0);
                    c = __builtin_amdgcn_mfma_f32_16x16x32_bf16(ah[mi], bl[nt], c, 0, 0, 0);
                    acc[mi][nt] = c;
                }
        }
    }

    // ---- part 2: A = AGG (dense fp32 global, K = 256) ----
    if (B2h) {
        #pragma unroll 1
        for (int kp = 0; kp < 8; ++kp) {
            short8 ah[2], al[2];
            #pragma unroll
            for (int mi = 0; mi < 2; ++mi) {
                const float* ap = AGGu + (size_t)(m0 + mi * 16 + fr) * H_DIM + kp * 32 + fq * 8;
                float4 v0 = *(const float4*)ap;
                float4 v1 = *(const float4*)(ap + 4);
                unsigned short h, l;
                split2(v0.x, h, l); ah[mi][0] = (short)h; al[mi][0] = (short)l;
                split2(v0.y, h, l); ah[mi][1] = (short)h; al[mi][1] = (short)l;
                split2(v0.z, h, l); ah[mi][2] = (short)h; al[mi][2] = (short)l;
                split2(v0.w, h, l); ah[mi][3] = (short)h; al[mi][3] = (short)l;
                split2(v1.x, h, l); ah[mi][4] = (short)h; al[mi][4] = (short)l;
                split2(v1.y, h, l); ah[mi][5] = (short)h; al[mi][5] = (short)l;
                split2(v1.z, h, l); ah[mi][6] = (short)h; al[mi][6] = (short)l;
                split2(v1.w, h, l); ah[mi][7] = (short)h; al[mi][7] = (short)l;
            }
            short8 bh[4], bl[4];
            #pragma unroll
            for (int nt = 0; nt < 4; ++nt) {
                size_t off = ((size_t)((rtbase + nt) * 8 + kp) * 64 + lane) * 8;
                bh[nt] = *(const short8*)(B2h + off);
                bl[nt] = *(const short8*)(B2l + off);
            }
            #pragma unroll
            for (int mi = 0; mi < 2; ++mi)
                #pragma unroll
                for (int nt = 0; nt < 4; ++nt) {
                    f32x4 c = acc[mi][nt];
                    c = __builtin_amdgcn_mfma_f32_16x16x32_bf16(ah[mi], bh[nt], c, 0, 0, 0);
                    c = __builtin_amdgcn_mfma_f32_16x16x32_bf16(al[mi], bh[nt], c, 0, 0, 0);
                    c = __builtin_amdgcn_mfma_f32_16x16x32_bf16(ah[mi], bl[nt], c, 0, 0, 0);
                    acc[mi][nt] = c;
                }
        }
    }

    // ---- epilogue: C[m = m0+mi*16+fq*4+r][n = wn+nt*16+fr] ----
    const float leak = leak_ptr[0], il = 1.0f - leak;
    #pragma unroll
    for (int mi = 0; mi < 2; ++mi)
        #pragma unroll
        for (int r = 0; r < 4; ++r) {
            int m = m0 + mi * 16 + fq * 4 + r;
            #pragma unroll
            for (int nt = 0; nt < 4; ++nt) {
                int n = wn + nt * 16 + fr;
                size_t idx = (size_t)m * H_DIM + n;
                float old = s_prev[idx];
                float pre = acc[mi][nt][r];
                float e = __expf(2.0f * pre);
                float th = 1.0f - 2.0f / (e + 1.0f);
                s_new[idx] = leak * th + il * old;
            }
        }
}

// ---------------- launch ----------------

extern "C" void kernel_launch(void* const* d_in, const int* in_sizes, int n_in,
                              void* d_out, int out_size, void* d_ws, size_t ws_size,
                              hipStream_t stream) {
    const float* x        = (const float*)d_in[0];
    const int*   edge     = (const int*)d_in[1];
    const float* w_in0    = (const float*)d_in[2];
    const float* w_rec0   = (const float*)d_in[3];
    const float* w_in1    = (const float*)d_in[4];
    const float* w_rec1   = (const float*)d_in[5];
    const float* leak_ptr = (const float*)d_in[6];

    const int* src = edge;
    const int* dst = edge + E_EDGES;

    char* ws = (char*)d_ws;
    size_t off = 0;
    auto alloc = [&](size_t bytes) -> char* {
        char* p = ws + off;
        off += (bytes + 255) & ~(size_t)255;
        return p;
    };
    const size_t state_bytes = (size_t)N_NODES * H_DIM * sizeof(float);
    // ping-pong buffers; s1 buffer 0 is d_out (t=7 writes buffer (7+1)&1 = 0)
    float* s0b[2]; float* s1b[2];
    s0b[0] = (float*)alloc(state_bytes);
    s0b[1] = (float*)alloc(state_bytes);
    s1b[0] = (float*)d_out;
    s1b[1] = (float*)alloc(state_bytes);
    float* AGG0 = (float*)alloc(state_bytes);
    float* AGG1 = (float*)alloc(state_bytes);
    unsigned short* w0h  = (unsigned short*)alloc(256 * 128 * 2);
    unsigned short* w0l  = (unsigned short*)alloc(256 * 128 * 2);
    unsigned short* wr0h = (unsigned short*)alloc(256 * 256 * 2);
    unsigned short* wr0l = (unsigned short*)alloc(256 * 256 * 2);
    unsigned short* w1h  = (unsigned short*)alloc(256 * 256 * 2);
    unsigned short* w1l  = (unsigned short*)alloc(256 * 256 * 2);
    unsigned short* wr1h = (unsigned short*)alloc(256 * 256 * 2);
    unsigned short* wr1l = (unsigned short*)alloc(256 * 256 * 2);
    int* row_ptr = (int*)alloc((N_NODES + 1) * sizeof(int));
    int* cursors = (int*)alloc(N_NODES * sizeof(int));
    int* counts  = (int*)alloc(N_NODES * sizeof(int));
    unsigned short* col = (unsigned short*)alloc((size_t)E_EDGES * sizeof(unsigned short));

    hipMemsetAsync(s0b[0], 0, state_bytes, stream);
    hipMemsetAsync(s1b[0], 0, state_bytes, stream);
    hipMemsetAsync(counts, 0, N_NODES * sizeof(int), stream);

    cvt_frag<<<16, 256, 0, stream>>>(w_in0, F_IN, w0h, w0l);
    cvt_frag<<<32, 256, 0, stream>>>(w_rec0, H_DIM, wr0h, wr0l);
    cvt_frag<<<32, 256, 0, stream>>>(w_in1, H_DIM, w1h, w1l);
    cvt_frag<<<32, 256, 0, stream>>>(w_rec1, H_DIM, wr1h, wr1l);

    count_kernel<<<(E_EDGES + 255) / 256, 256, 0, stream>>>(dst, counts, E_EDGES);
    scan_kernel<<<1, 1024, 0, stream>>>(counts, row_ptr, cursors, N_NODES);
    fill_kernel<<<(E_EDGES + 255) / 256, 256, 0, stream>>>(src, dst, cursors, col, E_EDGES);

    dim3 g_small(G_UPD);
    dim3 g_big(G_BIG);

    // Dependency schedule (s0(t) lives in s0b[(t+1)&1], s1(t) in s1b[(t+1)&1]):
    //   L0:  UPD0(0)                       (dense only; no gather)
    //   L1:  UPD1(0) + AGG0(1)             (gather s0(0))
    //   t=1..7:
    //     L_A: UPD0(t) + AGG1(t)           (gather s1(t-1))
    //     L_B: UPD1(t) + AGG0(t+1)         (gather s0(t); skipped at t=7)

    // L0 (update only, 256 threads)
    step_kernel<<<g_small, 256, 0, stream>>>(
        x, F_IN, s0b[0], w0h, w0l, nullptr, nullptr, nullptr, s0b[1],
        nullptr, nullptr, 0, row_ptr, col, leak_ptr);
    // L1
    step_kernel<<<g_big, 512, 0, stream>>>(
        s0b[1], H_DIM, s1b[0], w1h, w1l, nullptr, nullptr, nullptr, s1b[1],
        s0b[1], AGG0, 1, row_ptr, col, leak_ptr);

    for (int t = 1; t < T_STEPS; ++t) {
        const float* s0_prev = s0b[t & 1];        // s0(t-1)
        float* s0_cur        = s0b[(t + 1) & 1];  // s0(t)
        const float* s1_prev = s1b[t & 1];        // s1(t-1)
        float* s1_cur        = s1b[(t + 1) & 1];  // s1(t)
        const float* xt = x + (size_t)t * N_NODES * F_IN;

        // L_A: UPD0(t) + AGG1(t)
        step_kernel<<<g_big, 512, 0, stream>>>(
            xt, F_IN, s0_prev, w0h, w0l, wr0h, wr0l, AGG0, s0_cur,
            s1_prev, AGG1, 1, row_ptr, col, leak_ptr);

        // L_B: UPD1(t) + AGG0(t+1)
        if (t < T_STEPS - 1) {
            step_kernel<<<g_big, 512, 0, stream>>>(
                s0_cur, H_DIM, s1_prev, w1h, w1l, wr1h, wr1l, AGG1, s1_cur,
                s0_cur, AGG0, 1, row_ptr, col, leak_ptr);
        } else {
            step_kernel<<<g_small, 256, 0, stream>>>(
                s0_cur, H_DIM, s1_prev, w1h, w1l, wr1h, wr1l, AGG1, s1_cur,
                nullptr, nullptr, 0, row_ptr, col, leak_ptr);
        }
    }
}

// Round 4
// 1250.837 us; speedup vs baseline: 1.7987x; 1.7987x over previous
//
#include <hip/hip_runtime.h>
#include <math.h>

#define T_STEPS 8
#define N_NODES 20000
#define F_IN    128
#define H_DIM   256
#define E_EDGES 320000

#define G_UPD    625     // update tiles (20000/32)
#define G_AGG    5000    // 625 node-groups x 8 col-chunks

typedef __attribute__((ext_vector_type(8))) short short8;
typedef __attribute__((ext_vector_type(4))) float f32x4;

__device__ __forceinline__ void split2(float v, unsigned short& h, unsigned short& l) {
    unsigned vi = __float_as_uint(v);
    h = (unsigned short)(vi >> 16);
    float hf = __uint_as_float(vi & 0xffff0000u);
    l = (unsigned short)(__float_as_uint(v - hf) >> 16);
}

// ---------------- CSR build ----------------

__global__ void count_kernel(const int* __restrict__ dst, int* __restrict__ counts, int E) {
    int e = blockIdx.x * blockDim.x + threadIdx.x;
    if (e < E) atomicAdd(&counts[dst[e]], 1);
}

__global__ void scan_kernel(const int* __restrict__ counts, int* __restrict__ row_ptr,
                            int* __restrict__ cursors, int n) {
    __shared__ int buf[1024];
    __shared__ int carry_s;
    int tid = threadIdx.x;
    if (tid == 0) carry_s = 0;
    __syncthreads();
    for (int base = 0; base < n; base += 1024) {
        int i = base + tid;
        int v = (i < n) ? counts[i] : 0;
        buf[tid] = v;
        __syncthreads();
        for (int off = 1; off < 1024; off <<= 1) {
            int t = (tid >= off) ? buf[tid - off] : 0;
            __syncthreads();
            buf[tid] += t;
            __syncthreads();
        }
        int incl = buf[tid];
        int carry = carry_s;
        if (i < n) {
            int ex = carry + incl - v;
            row_ptr[i] = ex;
            cursors[i] = ex;
        }
        __syncthreads();
        if (tid == 1023) carry_s = carry + incl;
        __syncthreads();
    }
    if (tid == 0) row_ptr[n] = carry_s;
}

// col stored as ushort (N_NODES < 65536): halves index traffic, helps L2 residency
__global__ void fill_kernel(const int* __restrict__ src, const int* __restrict__ dst,
                            int* __restrict__ cursors, unsigned short* __restrict__ col, int E) {
    int e = blockIdx.x * blockDim.x + threadIdx.x;
    if (e < E) {
        int d = dst[e];
        int p = atomicAdd(&cursors[d], 1);
        col[p] = (unsigned short)src[e];
    }
}

// ---------------- weight fp32 -> MFMA-fragment-major bf16 hi/lo ----------------

__global__ void cvt_frag(const float* __restrict__ W, int K,
                         unsigned short* __restrict__ fh, unsigned short* __restrict__ fl) {
    int g = blockIdx.x * 256 + threadIdx.x;
    int KP32 = K >> 5;
    int total = (H_DIM / 16) * KP32 * 64;
    if (g >= total) return;
    int lane = g & 63;
    int kp = (g >> 6) % KP32;
    int rt = g / (KP32 << 6);
    int r = rt * 16 + (lane & 15);
    int c = kp * 32 + (lane >> 4) * 8;
    const float* p = W + (size_t)r * K + c;
    short8 h, l;
    #pragma unroll
    for (int j = 0; j < 8; ++j) {
        unsigned short hh, ll;
        split2(p[j], hh, ll);
        h[j] = (short)hh; l[j] = (short)ll;
    }
    *(short8*)(fh + (size_t)g * 8) = h;
    *(short8*)(fl + (size_t)g * 8) = l;
}

// ---------------- gather kernel (standalone dispatch) ----------------
// chunk = blockIdx&7 -> XCD pin (r2: FETCH 300->44 MB). Runs ALONE so the
// 2.56 MB per-XCD state slice stays L2-resident (r3 showed co-resident
// streaming waves evict it: FETCH 44->63 MB, dur 112->161 us).
// 5000 blocks x 256 thr, no LDS, ~8 blocks/CU: per wave 8 slots x 2 chains of
// 128 B segments in flight.

__global__ __launch_bounds__(256) void agg_kernel(
        const float* __restrict__ gsrc, float* __restrict__ gout,
        const int* __restrict__ row_ptr, const unsigned short* __restrict__ col) {
    const int tid = threadIdx.x;
    const int lane = tid & 63, w = tid >> 6;
    const int g = blockIdx.x;
    const int chunk = g & 7;       // XCD pin
    const int nb = g >> 3;
    const int slot = lane >> 3, comp = lane & 7;
    const float4* src4 = (const float4*)gsrc + (size_t)chunk * 8 + comp;
    #pragma unroll 1
    for (int i = 0; i < 8; ++i) {
        int r = nb * 32 + w * 8 + i;
        int beg = row_ptr[r], end = row_ptr[r + 1];
        float4 a = {0.f, 0.f, 0.f, 0.f};
        int j = beg + slot;
        for (; j + 8 < end; j += 16) {
            int i0 = col[j];
            int i1 = col[j + 8];
            float4 v0 = src4[(size_t)i0 * 64];
            float4 v1 = src4[(size_t)i1 * 64];
            a.x += v0.x; a.y += v0.y; a.z += v0.z; a.w += v0.w;
            a.x += v1.x; a.y += v1.y; a.z += v1.z; a.w += v1.w;
        }
        if (j < end) {
            int i0 = col[j];
            float4 v0 = src4[(size_t)i0 * 64];
            a.x += v0.x; a.y += v0.y; a.z += v0.z; a.w += v0.w;
        }
        #pragma unroll
        for (int m = 8; m < 64; m <<= 1) {
            a.x += __shfl_xor(a.x, m);
            a.y += __shfl_xor(a.y, m);
            a.z += __shfl_xor(a.z, m);
            a.w += __shfl_xor(a.w, m);
        }
        if (slot == 0)
            *(float4*)(gout + (size_t)r * 256 + chunk * 32 + comp * 4) = a;
    }
}

// ---------------- update kernel ----------------
// Pure dense MFMA update, 32 rows x 256 cols per block, 4 waves.
// Part 1: A = inp (fp32 global), Part 2: A = AGG (fp32 global).
// Merged form (r1 schedule): task = blockIdx&1 interleaves the two independent
// updates UPD1(t) / UPD0(t+1) -> 1250 blocks (~4.9/CU) for latency hiding.

__device__ __forceinline__ void upd_body(
        const float* __restrict__ A1, int K1,
        const float* __restrict__ s_prev,
        const unsigned short* __restrict__ B1h, const unsigned short* __restrict__ B1l,
        const unsigned short* __restrict__ B2h, const unsigned short* __restrict__ B2l,
        const float* __restrict__ AGGu,
        float* __restrict__ s_new,
        const float* __restrict__ leak_ptr, int m0) {
    const int tid = threadIdx.x;
    const int lane = tid & 63, w = tid >> 6;
    const int fr = lane & 15, fq = lane >> 4;
    const int wn = w * 64;
    const int rtbase = w * 4;

    f32x4 acc[2][4];
    #pragma unroll
    for (int mi = 0; mi < 2; ++mi)
        #pragma unroll
        for (int nt = 0; nt < 4; ++nt)
            acc[mi][nt] = (f32x4){0.f, 0.f, 0.f, 0.f};

    // ---- part 1: dense A1 ----
    {
        const int KP32 = K1 >> 5;
        #pragma unroll 1
        for (int kp = 0; kp < KP32; ++kp) {
            short8 ah[2], al[2];
            #pragma unroll
            for (int mi = 0; mi < 2; ++mi) {
                const float* ap = A1 + (size_t)(m0 + mi * 16 + fr) * K1 + kp * 32 + fq * 8;
                float4 v0 = *(const float4*)ap;
                float4 v1 = *(const float4*)(ap + 4);
                unsigned short h, l;
                split2(v0.x, h, l); ah[mi][0] = (short)h; al[mi][0] = (short)l;
                split2(v0.y, h, l); ah[mi][1] = (short)h; al[mi][1] = (short)l;
                split2(v0.z, h, l); ah[mi][2] = (short)h; al[mi][2] = (short)l;
                split2(v0.w, h, l); ah[mi][3] = (short)h; al[mi][3] = (short)l;
                split2(v1.x, h, l); ah[mi][4] = (short)h; al[mi][4] = (short)l;
                split2(v1.y, h, l); ah[mi][5] = (short)h; al[mi][5] = (short)l;
                split2(v1.z, h, l); ah[mi][6] = (short)h; al[mi][6] = (short)l;
                split2(v1.w, h, l); ah[mi][7] = (short)h; al[mi][7] = (short)l;
            }
            short8 bh[4], bl[4];
            #pragma unroll
            for (int nt = 0; nt < 4; ++nt) {
                size_t off = ((size_t)((rtbase + nt) * KP32 + kp) * 64 + lane) * 8;
                bh[nt] = *(const short8*)(B1h + off);
                bl[nt] = *(const short8*)(B1l + off);
            }
            #pragma unroll
            for (int mi = 0; mi < 2; ++mi)
                #pragma unroll
                for (int nt = 0; nt < 4; ++nt) {
                    f32x4 c = acc[mi][nt];
                    c = __builtin_amdgcn_mfma_f32_16x16x32_bf16(ah[mi], bh[nt], c, 0, 0, 0);
                    c = __builtin_amdgcn_mfma_f32_16x16x32_bf16(al[mi], bh[nt], c, 0, 0, 0);
                    c = __builtin_amdgcn_mfma_f32_16x16x32_bf16(ah[mi], bl[nt], c, 0, 0, 0);
                    acc[mi][nt] = c;
                }
        }
    }

    // ---- part 2: A = AGG (dense fp32 global, K = 256) ----
    if (B2h) {
        #pragma unroll 1
        for (int kp = 0; kp < 8; ++kp) {
            short8 ah[2], al[2];
            #pragma unroll
            for (int mi = 0; mi < 2; ++mi) {
                const float* ap = AGGu + (size_t)(m0 + mi * 16 + fr) * H_DIM + kp * 32 + fq * 8;
                float4 v0 = *(const float4*)ap;
                float4 v1 = *(const float4*)(ap + 4);
                unsigned short h, l;
                split2(v0.x, h, l); ah[mi][0] = (short)h; al[mi][0] = (short)l;
                split2(v0.y, h, l); ah[mi][1] = (short)h; al[mi][1] = (short)l;
                split2(v0.z, h, l); ah[mi][2] = (short)h; al[mi][2] = (short)l;
                split2(v0.w, h, l); ah[mi][3] = (short)h; al[mi][3] = (short)l;
                split2(v1.x, h, l); ah[mi][4] = (short)h; al[mi][4] = (short)l;
                split2(v1.y, h, l); ah[mi][5] = (short)h; al[mi][5] = (short)l;
                split2(v1.z, h, l); ah[mi][6] = (short)h; al[mi][6] = (short)l;
                split2(v1.w, h, l); ah[mi][7] = (short)h; al[mi][7] = (short)l;
            }
            short8 bh[4], bl[4];
            #pragma unroll
            for (int nt = 0; nt < 4; ++nt) {
                size_t off = ((size_t)((rtbase + nt) * 8 + kp) * 64 + lane) * 8;
                bh[nt] = *(const short8*)(B2h + off);
                bl[nt] = *(const short8*)(B2l + off);
            }
            #pragma unroll
            for (int mi = 0; mi < 2; ++mi)
                #pragma unroll
                for (int nt = 0; nt < 4; ++nt) {
                    f32x4 c = acc[mi][nt];
                    c = __builtin_amdgcn_mfma_f32_16x16x32_bf16(ah[mi], bh[nt], c, 0, 0, 0);
                    c = __builtin_amdgcn_mfma_f32_16x16x32_bf16(al[mi], bh[nt], c, 0, 0, 0);
                    c = __builtin_amdgcn_mfma_f32_16x16x32_bf16(ah[mi], bl[nt], c, 0, 0, 0);
                    acc[mi][nt] = c;
                }
        }
    }

    // ---- epilogue: C[m = m0+mi*16+fq*4+r][n = wn+nt*16+fr] ----
    const float leak = leak_ptr[0], il = 1.0f - leak;
    #pragma unroll
    for (int mi = 0; mi < 2; ++mi)
        #pragma unroll
        for (int r = 0; r < 4; ++r) {
            int m = m0 + mi * 16 + fq * 4 + r;
            #pragma unroll
            for (int nt = 0; nt < 4; ++nt) {
                int n = wn + nt * 16 + fr;
                size_t idx = (size_t)m * H_DIM + n;
                float old = s_prev[idx];
                float pre = acc[mi][nt][r];
                float e = __expf(2.0f * pre);
                float th = 1.0f - 2.0f / (e + 1.0f);
                s_new[idx] = leak * th + il * old;
            }
        }
}

__global__ __launch_bounds__(256) void upd_kernel(
        const float* __restrict__ A1a, int K1a, const float* __restrict__ spa,
        const unsigned short* __restrict__ B1ha, const unsigned short* __restrict__ B1la,
        const unsigned short* __restrict__ B2ha, const unsigned short* __restrict__ B2la,
        const float* __restrict__ AGGa, float* __restrict__ sna,
        const float* __restrict__ A1b, int K1b, const float* __restrict__ spb,
        const unsigned short* __restrict__ B1hb, const unsigned short* __restrict__ B1lb,
        const unsigned short* __restrict__ B2hb, const unsigned short* __restrict__ B2lb,
        const float* __restrict__ AGGb, float* __restrict__ snb,
        const float* __restrict__ leak_ptr, int merged) {
    if (merged) {
        const int task = blockIdx.x & 1;
        const int m0 = (blockIdx.x >> 1) * 32;
        if (task == 0)
            upd_body(A1a, K1a, spa, B1ha, B1la, B2ha, B2la, AGGa, sna, leak_ptr, m0);
        else
            upd_body(A1b, K1b, spb, B1hb, B1lb, B2hb, B2lb, AGGb, snb, leak_ptr, m0);
    } else {
        upd_body(A1a, K1a, spa, B1ha, B1la, B2ha, B2la, AGGa, sna, leak_ptr, blockIdx.x * 32);
    }
}

// ---------------- launch ----------------

extern "C" void kernel_launch(void* const* d_in, const int* in_sizes, int n_in,
                              void* d_out, int out_size, void* d_ws, size_t ws_size,
                              hipStream_t stream) {
    const float* x        = (const float*)d_in[0];
    const int*   edge     = (const int*)d_in[1];
    const float* w_in0    = (const float*)d_in[2];
    const float* w_rec0   = (const float*)d_in[3];
    const float* w_in1    = (const float*)d_in[4];
    const float* w_rec1   = (const float*)d_in[5];
    const float* leak_ptr = (const float*)d_in[6];

    const int* src = edge;
    const int* dst = edge + E_EDGES;

    char* ws = (char*)d_ws;
    size_t off = 0;
    auto alloc = [&](size_t bytes) -> char* {
        char* p = ws + off;
        off += (bytes + 255) & ~(size_t)255;
        return p;
    };
    const size_t state_bytes = (size_t)N_NODES * H_DIM * sizeof(float);
    // ping-pong buffers; s1 buffer 0 is d_out (s1(7) lands in s1b[(7+1)&1] = s1b[0])
    float* s0b[2]; float* s1b[2];
    s0b[0] = (float*)alloc(state_bytes);
    s0b[1] = (float*)alloc(state_bytes);
    s1b[0] = (float*)d_out;
    s1b[1] = (float*)alloc(state_bytes);
    float* AGG0 = (float*)alloc(state_bytes);
    float* AGG1 = (float*)alloc(state_bytes);
    unsigned short* w0h  = (unsigned short*)alloc(256 * 128 * 2);
    unsigned short* w0l  = (unsigned short*)alloc(256 * 128 * 2);
    unsigned short* wr0h = (unsigned short*)alloc(256 * 256 * 2);
    unsigned short* wr0l = (unsigned short*)alloc(256 * 256 * 2);
    unsigned short* w1h  = (unsigned short*)alloc(256 * 256 * 2);
    unsigned short* w1l  = (unsigned short*)alloc(256 * 256 * 2);
    unsigned short* wr1h = (unsigned short*)alloc(256 * 256 * 2);
    unsigned short* wr1l = (unsigned short*)alloc(256 * 256 * 2);
    int* row_ptr = (int*)alloc((N_NODES + 1) * sizeof(int));
    int* cursors = (int*)alloc(N_NODES * sizeof(int));
    int* counts  = (int*)alloc(N_NODES * sizeof(int));
    unsigned short* col = (unsigned short*)alloc((size_t)E_EDGES * sizeof(unsigned short));

    hipMemsetAsync(s0b[0], 0, state_bytes, stream);
    hipMemsetAsync(s1b[0], 0, state_bytes, stream);
    hipMemsetAsync(counts, 0, N_NODES * sizeof(int), stream);

    cvt_frag<<<16, 256, 0, stream>>>(w_in0, F_IN, w0h, w0l);
    cvt_frag<<<32, 256, 0, stream>>>(w_rec0, H_DIM, wr0h, wr0l);
    cvt_frag<<<32, 256, 0, stream>>>(w_in1, H_DIM, w1h, w1l);
    cvt_frag<<<32, 256, 0, stream>>>(w_rec1, H_DIM, wr1h, wr1l);

    count_kernel<<<(E_EDGES + 255) / 256, 256, 0, stream>>>(dst, counts, E_EDGES);
    scan_kernel<<<1, 1024, 0, stream>>>(counts, row_ptr, cursors, N_NODES);
    fill_kernel<<<(E_EDGES + 255) / 256, 256, 0, stream>>>(src, dst, cursors, col, E_EDGES);

    dim3 g_upd1(G_UPD);      // 625
    dim3 g_upd2(2 * G_UPD);  // 1250 merged
    dim3 g_agg(G_AGG);       // 5000

    // Serial dependency-exact schedule (s0(t) in s0b[(t+1)&1], s1(t) in s1b[(t+1)&1]):
    //   UPD0(0)                      dense only
    //   AGG0(1)                      gather s0(0)
    //   t = 0..6:
    //     UPDm(t) = UPD1(t) + UPD0(t+1)    (independent pair, merged)
    //     AGG1(t+1)                  gather s1(t)
    //     AGG0(t+2) if t+2 <= 7      gather s0(t+1)
    //   UPD1(7)                      writes d_out

    // UPD0(0): A=x(0), no AGG
    upd_kernel<<<g_upd1, 256, 0, stream>>>(
        x, F_IN, s0b[0], w0h, w0l, nullptr, nullptr, nullptr, s0b[1],
        nullptr, 0, nullptr, nullptr, nullptr, nullptr, nullptr, nullptr, nullptr,
        leak_ptr, 0);
    // AGG0(1): gather s0(0)
    agg_kernel<<<g_agg, 256, 0, stream>>>(s0b[1], AGG0, row_ptr, col);

    for (int t = 0; t < 7; ++t) {
        const float* s0_t  = s0b[(t + 1) & 1];   // s0(t)
        float* s0_n        = s0b[t & 1];         // s0(t+1) dest
        const float* s1_p  = s1b[t & 1];         // s1(t-1)
        float* s1_t        = s1b[(t + 1) & 1];   // s1(t) dest
        const float* xt1 = x + (size_t)(t + 1) * N_NODES * F_IN;
        int dg1 = (t > 0) ? 1 : 0;               // s1(-1) = 0 -> skip AGG term

        // UPDm(t): task a = UPD1(t), task b = UPD0(t+1)
        upd_kernel<<<g_upd2, 256, 0, stream>>>(
            s0_t, H_DIM, s1_p, w1h, w1l,
            dg1 ? wr1h : nullptr, dg1 ? wr1l : nullptr, AGG1, s1_t,
            xt1, F_IN, s0_t, w0h, w0l, wr0h, wr0l, AGG0, s0_n,
            leak_ptr, 1);

        // AGG1(t+1): gather s1(t)
        agg_kernel<<<g_agg, 256, 0, stream>>>(s1_t, AGG1, row_ptr, col);
        // AGG0(t+2): gather s0(t+1)
        if (t + 2 <= 7)
            agg_kernel<<<g_agg, 256, 0, stream>>>(s0_n, AGG0, row_ptr, col);
    }

    // UPD1(7): A = s0(7) = s0b[0], sp = s1(6) = s1b[1], writes s1b[0] = d_out
    upd_kernel<<<g_upd1, 256, 0, stream>>>(
        s0b[0], H_DIM, s1b[1], w1h, w1l, wr1h, wr1l, AGG1, s1b[0],
        nullptr, 0, nullptr, nullptr, nullptr, nullptr, nullptr, nullptr, nullptr,
        leak_ptr, 0);
}